// Round 4
// baseline (97.440 us; speedup 1.0000x reference)
//
#include <hip/hip_runtime.h>
#include <hip/hip_cooperative_groups.h>
#include <math.h>

namespace cg = cooperative_groups;

// dims: B=4096, D=64, K=64, DM=512
// Workspace layout (float offsets)
#define WS_INV    0
#define WS_INVSV  1
#define WS_BOVW   2
#define WS_BVWO   3
#define WS_N2V    4
#define WS_COLSUM 64          // 64
#define WS_A      128         // 64*64 = 4096
#define WS_WO0    4224        // 512
#define WS_QZB    4736        // 512
#define WS_CK0    5248        // 64
#define WS_CVW    5312        // 64
#define WS_NY2    5376        // 64
#define WS_YT     5440        // 4096
#define WS_T1     16384       // T1t[f][k] 512*64
#define WS_V1     49152       // V1t[e][k] 512*64
#define WS_P1     81920       // P1[f][d]  512*64
#define WS_GP     114688      // 4 * 4096 partial Gt[d][k]

#define FUSED_LDSB (36928 * 4)   // 147712 B -> 1 block/CU
#define MAIN_LDSB  (8448 * 4)

__device__ __forceinline__ float wave_sum(float x) {
#pragma unroll
    for (int o = 32; o; o >>= 1) x += __shfl_xor(x, o);
    return x;
}

__device__ __forceinline__ float block_sum512(float v, float* red) {
    float s = wave_sum(v);
    const int wid = threadIdx.x >> 6;
    __syncthreads();
    if ((threadIdx.x & 63) == 0) red[wid] = s;
    __syncthreads();
    float t2 = 0.0f;
#pragma unroll
    for (int i = 0; i < 8; ++i) t2 += red[i];
    return t2;
}

// ===========================================================================
// Phase A (level-0, inputs only), roles by blk:
//  0..127  : T1t & V1t (CE staged [64][513], warp-c-split, 4+4 rows)
//  128..191: P1[f][d] 8 f-rows (zW staged natural)
//  192..199: A = zW^T zW rows (+ colsum on 192)
//  200..207: qzb = Wq@zb + bq
//  208..215: wo0 = Wo^T vW
//  216     : n2v, bo.vW, chart-center projection -> Yt, ny2
// ===========================================================================
__device__ __forceinline__ void phaseA(
    const int blk, const int t, float* sm,
    const float* __restrict__ zW, const float* __restrict__ zb,
    const float* __restrict__ Wq, const float* __restrict__ bq,
    const float* __restrict__ Wk, const float* __restrict__ Wv,
    const float* __restrict__ Wo, const float* __restrict__ ce,
    const float* __restrict__ cc, const float* __restrict__ vW,
    const float* __restrict__ bo, float* __restrict__ ws)
{
    const int lane = t & 63, w = t >> 6;

    if (blk < 128) {
        const int f0 = blk * 4;
        float* ces = sm;            // 64*513
        float* wkv = sm + 32832;    // 8*512
#pragma unroll 4
        for (int i = 0; i < 64; ++i) {
            const int idx = i * 512 + t;
            ces[(idx >> 9) * 513 + (idx & 511)] = ce[idx];
        }
        {
            const float4* Wk4 = (const float4*)Wk;
            const float4* Wv4 = (const float4*)Wv;
            float4* wkv4 = (float4*)wkv;
#pragma unroll
            for (int i = 0; i < 2; ++i) {
                const int idx = i * 512 + t;
                const int a = idx >> 7, c4 = idx & 127;
                wkv4[idx] = (a < 4) ? Wk4[(f0 + a) * 128 + c4]
                                    : Wv4[(f0 + a - 4) * 128 + c4];
            }
        }
        __syncthreads();
        float acc[8];
#pragma unroll
        for (int a = 0; a < 8; ++a) acc[a] = 0.0f;
        const int c0 = w * 64;
#pragma unroll 2
        for (int q4 = 0; q4 < 16; ++q4) {
            const int c = c0 + q4 * 4;
            const float cv0 = ces[lane * 513 + c + 0];
            const float cv1 = ces[lane * 513 + c + 1];
            const float cv2 = ces[lane * 513 + c + 2];
            const float cv3 = ces[lane * 513 + c + 3];
#pragma unroll
            for (int a = 0; a < 8; ++a) {
                const float4 wv4 = *(const float4*)&wkv[a * 512 + c];
                acc[a] = fmaf(wv4.x, cv0, acc[a]);
                acc[a] = fmaf(wv4.y, cv1, acc[a]);
                acc[a] = fmaf(wv4.z, cv2, acc[a]);
                acc[a] = fmaf(wv4.w, cv3, acc[a]);
            }
        }
        __syncthreads();
        float* part = sm;                              // reuse, 64*65
#pragma unroll
        for (int a = 0; a < 8; ++a) part[(a * 8 + w) * 65 + lane] = acc[a];
        __syncthreads();
        {
            float s = 0.0f;
#pragma unroll
            for (int ww = 0; ww < 8; ++ww) s += part[(w * 8 + ww) * 65 + lane];
            if (w < 4) ws[WS_T1 + (f0 + w) * 64 + lane] = s;
            else       ws[WS_V1 + (f0 + w - 4) * 64 + lane] = s;
        }

    } else if (blk < 192) {
        const int f0 = (blk - 128) * 8;
        float* zl = sm;             // 512*64
        float* wq = sm + 32768;     // 8*512
        {
            const float4* zW4 = (const float4*)zW;
            float4* zl4 = (float4*)zl;
#pragma unroll 4
            for (int i = 0; i < 16; ++i) zl4[i * 512 + t] = zW4[i * 512 + t];
            const float4* Wq4 = (const float4*)Wq;
            float4* wq4 = (float4*)wq;
#pragma unroll
            for (int i = 0; i < 2; ++i)
                wq4[i * 512 + t] = Wq4[f0 * 128 + i * 512 + t];
        }
        __syncthreads();
        float acc[8];
#pragma unroll
        for (int a = 0; a < 8; ++a) acc[a] = 0.0f;
        const int e0 = w * 64;
#pragma unroll 2
        for (int q4 = 0; q4 < 16; ++q4) {
            const int e = e0 + q4 * 4;
            const float z0 = zl[(e + 0) * 64 + lane];
            const float z1 = zl[(e + 1) * 64 + lane];
            const float z2 = zl[(e + 2) * 64 + lane];
            const float z3 = zl[(e + 3) * 64 + lane];
#pragma unroll
            for (int fi = 0; fi < 8; ++fi) {
                const float4 q4v = *(const float4*)&wq[fi * 512 + e];
                acc[fi] = fmaf(q4v.x, z0, acc[fi]);
                acc[fi] = fmaf(q4v.y, z1, acc[fi]);
                acc[fi] = fmaf(q4v.z, z2, acc[fi]);
                acc[fi] = fmaf(q4v.w, z3, acc[fi]);
            }
        }
        __syncthreads();
        float* part = sm;
#pragma unroll
        for (int a = 0; a < 8; ++a) part[(a * 8 + w) * 65 + lane] = acc[a];
        __syncthreads();
        {
            float s = 0.0f;
#pragma unroll
            for (int ww = 0; ww < 8; ++ww) s += part[(w * 8 + ww) * 65 + lane];
            ws[WS_P1 + (f0 + w) * 64 + lane] = s;
        }

    } else if (blk < 200) {
        const int r0 = (blk - 192) * 8;
        float* zl = sm;
        {
            const float4* zW4 = (const float4*)zW;
            float4* zl4 = (float4*)zl;
#pragma unroll 4
            for (int i = 0; i < 16; ++i) zl4[i * 512 + t] = zW4[i * 512 + t];
        }
        __syncthreads();
        float acc[8];
#pragma unroll
        for (int a = 0; a < 8; ++a) acc[a] = 0.0f;
        float cs = 0.0f;
        const int e0 = w * 64;
#pragma unroll 2
        for (int q4 = 0; q4 < 16; ++q4) {
            const int e = e0 + q4 * 4;
#pragma unroll
            for (int j = 0; j < 4; ++j) {
                const float zv = zl[(e + j) * 64 + lane];
                cs += zv;
                const float4 b0 = *(const float4*)&zl[(e + j) * 64 + r0];
                const float4 b1 = *(const float4*)&zl[(e + j) * 64 + r0 + 4];
                acc[0] = fmaf(b0.x, zv, acc[0]);
                acc[1] = fmaf(b0.y, zv, acc[1]);
                acc[2] = fmaf(b0.z, zv, acc[2]);
                acc[3] = fmaf(b0.w, zv, acc[3]);
                acc[4] = fmaf(b1.x, zv, acc[4]);
                acc[5] = fmaf(b1.y, zv, acc[5]);
                acc[6] = fmaf(b1.z, zv, acc[6]);
                acc[7] = fmaf(b1.w, zv, acc[7]);
            }
        }
        __syncthreads();
        float* part = sm;            // 64*65
        float* part2 = sm + 4160;    // 8*65
#pragma unroll
        for (int a = 0; a < 8; ++a) part[(a * 8 + w) * 65 + lane] = acc[a];
        if (blk == 192) part2[w * 65 + lane] = cs;
        __syncthreads();
        {
            float s = 0.0f;
#pragma unroll
            for (int ww = 0; ww < 8; ++ww) s += part[(w * 8 + ww) * 65 + lane];
            ws[WS_A + (r0 + w) * 64 + lane] = s;
        }
        if (blk == 192 && t < 64) {
            float s = 0.0f;
#pragma unroll
            for (int ww = 0; ww < 8; ++ww) s += part2[ww * 65 + t];
            ws[WS_COLSUM + t] = s;
        }

    } else if (blk < 208) {
        const int f0 = (blk - 200) * 64;
        float zbr[8];
#pragma unroll
        for (int i = 0; i < 8; ++i) zbr[i] = zb[i * 64 + lane];
#pragma unroll
        for (int ff = 0; ff < 8; ++ff) {
            const int f = f0 + w * 8 + ff;
            float s = 0.0f;
#pragma unroll
            for (int i = 0; i < 8; ++i)
                s = fmaf(Wq[f * 512 + i * 64 + lane], zbr[i], s);
            s = wave_sum(s);
            if (lane == 0) ws[WS_QZB + f] = s + bq[f];
        }

    } else if (blk < 216) {
        const int e0 = (blk - 208) * 64;
        float s = 0.0f;
#pragma unroll 4
        for (int gi = 0; gi < 64; ++gi) {
            const int g = w * 64 + gi;
            s = fmaf(Wo[g * 512 + e0 + lane], vW[g], s);
        }
        float* part = sm;
        part[w * 65 + lane] = s;
        __syncthreads();
        if (t < 64) {
            float o = 0.0f;
#pragma unroll
            for (int ww = 0; ww < 8; ++ww) o += part[ww * 65 + t];
            ws[WS_WO0 + e0 + t] = o;
        }

    } else if (blk == 216) {
        float* red = sm;
        const float vwt = vW[t];
        const float n2v = block_sum512(vwt * vwt, red);
        if (t == 0) ws[WS_N2V] = n2v;
        const float bv_ = block_sum512(bo[t] * vwt, red);
        if (t == 0) ws[WS_BOVW] = bv_;
        if (t < 64) {
            float n2 = 0.0f;
            for (int dd = 0; dd < 64; ++dd) {
                const float c = cc[t * 64 + dd];
                n2 = fmaf(c, c, n2);
            }
            const float n = sqrtf(n2);
            const float scale = fminf(1.0f, (1.0f - 1e-5f) / fmaxf(n, 1e-12f));
            float s2 = 0.0f;
            for (int dd = 0; dd < 64; ++dd) {
                const float yv = cc[t * 64 + dd] * scale;
                ws[WS_YT + dd * 64 + t] = yv;
                s2 = fmaf(yv, yv, s2);
            }
            ws[WS_NY2 + t] = s2;
        }
    }
}

// ===========================================================================
// Phase B (level-1), roles by blk:
//  0   : sigma power-iteration on A (1 wave) + bv.wo0 + sigma_v closed form
//  1,2 : cvw0 = V1 @ wo0 ; ck0 = T1 @ qzb
//  3..6: Gt partials over 128-f slices
// ===========================================================================
__device__ __forceinline__ void phaseB(
    const int blk, const int t, float* sm,
    const float* __restrict__ bv, float* __restrict__ ws)
{
    const int lane = t & 63, w = t >> 6;

    if (blk == 0) {
        float* As = sm;   // 64*65
#pragma unroll
        for (int i = 0; i < 8; ++i) {
            const int idx = i * 512 + t;
            As[(idx >> 6) * 65 + (idx & 63)] = ws[WS_A + idx];
        }
        __syncthreads();
        if (w == 0) {
            const int d = lane;
            const float u0val = 1.0f / (sqrtf(512.0f) + 1e-12f);
            const float x = ws[WS_COLSUM + d] * u0val;
            const float nx = sqrtf(wave_sum(x * x));
            float v = x / (nx + 1e-12f);
            float mv;
            for (int it = 0; it < 4; ++it) {
                mv = 0.0f;
                for (int j = 0; j < 64; ++j)
                    mv = fmaf(As[j * 65 + d], __shfl(v, j), mv);
                const float s1 = wave_sum(mv * v);
                const float s2 = wave_sum(mv * mv);
                const float n = sqrtf(s1);
                const float inv1 = 1.0f / (n + 1e-12f);
                const float ny = sqrtf(s2) * inv1;
                v = mv * inv1 / (ny + 1e-12f);
            }
            mv = 0.0f;
            for (int j = 0; j < 64; ++j)
                mv = fmaf(As[j * 65 + d], __shfl(v, j), mv);
            const float n5sq = wave_sum(mv * v);
            const float n5 = sqrtf(n5sq);
            const float sig = n5sq / (n5 + 1e-12f);
            if (lane == 0) ws[WS_INV] = 1.0f / sig;
        } else if (w == 1) {
            float s = 0.0f;
#pragma unroll
            for (int i = 0; i < 8; ++i)
                s = fmaf(bv[i * 64 + lane], ws[WS_WO0 + i * 64 + lane], s);
            s = wave_sum(s);
            if (lane == 0) ws[WS_BVWO] = s;
        } else if (w == 2 && lane == 0) {
            const float n2 = ws[WS_N2V];
            const float rn = sqrtf(n2);
            float u = 1.0f / (1.0f + 1e-12f), s = 0.0f;
            for (int it = 0; it < 5; ++it) {
                const float nv = fabsf(u) * rn;
                const float vs = u / (nv + 1e-12f);
                s = n2 * vs;
                u = s / (fabsf(s) + 1e-12f);
            }
            ws[WS_INVSV] = 1.0f / (u * s);
        }

    } else if (blk < 3) {
        const int mat = (blk == 1) ? WS_V1 : WS_T1;
        const int vec = (blk == 1) ? WS_WO0 : WS_QZB;
        const int dst = (blk == 1) ? WS_CVW : WS_CK0;
        float s = 0.0f;
#pragma unroll 4
        for (int i = 0; i < 64; ++i) {
            const int e = w * 64 + i;
            s = fmaf(ws[mat + e * 64 + lane], ws[vec + e], s);
        }
        float* part = sm;
        part[w * 65 + lane] = s;
        __syncthreads();
        if (t < 64) {
            float o = 0.0f;
#pragma unroll
            for (int ww = 0; ww < 8; ++ww) o += part[ww * 65 + t];
            ws[dst + t] = o;
        }

    } else if (blk < 7) {
        const int p = blk - 3;
        const int f0 = p * 128;
        float* T1s = sm;           // 128*64
        float* P1s = sm + 8192;    // 128*64
        {
            const float4* a4 = (const float4*)&ws[WS_T1 + f0 * 64];
            const float4* b4 = (const float4*)&ws[WS_P1 + f0 * 64];
            float4* T14 = (float4*)T1s;
            float4* P14 = (float4*)P1s;
#pragma unroll
            for (int i = 0; i < 4; ++i) {
                T14[i * 512 + t] = a4[i * 512 + t];
                P14[i * 512 + t] = b4[i * 512 + t];
            }
        }
        __syncthreads();
        float acc[8];
#pragma unroll
        for (int j = 0; j < 8; ++j) acc[j] = 0.0f;
        const int d0 = w * 8;
#pragma unroll 2
        for (int f = 0; f < 128; ++f) {
            const float a = T1s[f * 64 + lane];
            const float4 p0 = *(const float4*)&P1s[f * 64 + d0];
            const float4 p1 = *(const float4*)&P1s[f * 64 + d0 + 4];
            acc[0] = fmaf(a, p0.x, acc[0]);
            acc[1] = fmaf(a, p0.y, acc[1]);
            acc[2] = fmaf(a, p0.z, acc[2]);
            acc[3] = fmaf(a, p0.w, acc[3]);
            acc[4] = fmaf(a, p1.x, acc[4]);
            acc[5] = fmaf(a, p1.y, acc[5]);
            acc[6] = fmaf(a, p1.z, acc[6]);
            acc[7] = fmaf(a, p1.w, acc[7]);
        }
#pragma unroll
        for (int j = 0; j < 8; ++j)
            ws[WS_GP + p * 4096 + (d0 + j) * 64 + lane] = acc[j];
    }
}

// ===========================================================================
// Phase C: main. 256 blocks x 512 threads; each wave 2 rows, lane = k.
// ===========================================================================
__device__ __forceinline__ void phaseC(
    const int blk, const int t, float* sm,
    const float* __restrict__ z, const float* __restrict__ rw,
    const float* __restrict__ geo, const float* __restrict__ vb,
    const float* __restrict__ ws, float* __restrict__ out)
{
    float* sGt  = sm;          // 4096
    float* sYt  = sm + 4096;   // 4096
    float* sCvw = sm + 8192;   // 64
    float* sCk0 = sm + 8256;   // 64
    float* sNy2 = sm + 8320;   // 64
    float* sSc  = sm + 8384;   // 2
    const float inv_s = ws[WS_INV];
    const float inv_sv = ws[WS_INVSV];
    for (int i = t; i < 4096; i += 512) {
        sGt[i] = inv_s * (ws[WS_GP + i] + ws[WS_GP + 4096 + i]
                        + ws[WS_GP + 8192 + i] + ws[WS_GP + 12288 + i]);
        sYt[i] = ws[WS_YT + i];
    }
    if (t < 64) {
        sCvw[t] = inv_sv * ws[WS_CVW + t];
        sCk0[t] = ws[WS_CK0 + t];
        sNy2[t] = ws[WS_NY2 + t];
    }
    if (t == 0) {
        sSc[0] = inv_sv * (ws[WS_BVWO] + ws[WS_BOVW]) + vb[0];
        sSc[1] = geo[0];
    }
    __syncthreads();
    const int wid = t >> 6, lane = t & 63;
    const float gs = sSc[1], cst = sSc[0];
    const float rs512 = 0.04419417382415922f;   // 1/sqrt(512)
#pragma unroll
    for (int r = 0; r < 2; ++r) {
        const int b = blk * 16 + wid * 2 + r;
        const float zl = z[b * 64 + lane];
        const float rwk = rw[b * 64 + lane];
        float dot = 0.0f, diff2 = 0.0f, nz2 = 0.0f;
#pragma unroll 8
        for (int dd = 0; dd < 64; ++dd) {
            const float zd = __shfl(zl, dd);
            nz2 = fmaf(zd, zd, nz2);
            dot = fmaf(zd, sGt[dd * 64 + lane], dot);
            const float df = zd - sYt[dd * 64 + lane];
            diff2 = fmaf(df, df, diff2);
        }
        const float den = (1.0f - nz2) * (1.0f - sNy2[lane]);
        float arg = 1.0f + 2.0f * diff2 / fmaxf(den, 1e-12f);
        arg = fmaxf(arg, 1.0f + 1e-7f);
        const float dg = acoshf(arg);
        const float score = rwk * (dot + sCk0[lane]) * rs512 - gs * dg * dg;
        float m = score;
#pragma unroll
        for (int o = 32; o; o >>= 1) m = fmaxf(m, __shfl_xor(m, o));
        const float e = expf(score - m);
        float s1 = e, s2 = e * rwk * sCvw[lane];
#pragma unroll
        for (int o = 32; o; o >>= 1) { s1 += __shfl_xor(s1, o); s2 += __shfl_xor(s2, o); }
        if (lane == 0) out[b] = s2 / s1 + cst;
    }
}

// ===========================================================================
// Fused cooperative kernel: 256 blocks x 512 threads, 1 block/CU.
// ===========================================================================
__global__ __launch_bounds__(512, 2) void k_fused(
    const float* zW, const float* zb, const float* Wq, const float* bq,
    const float* Wk, const float* Wv, const float* Wo, const float* ce,
    const float* cc, const float* vW, const float* bo, const float* bv,
    const float* z, const float* rw, const float* geo, const float* vb,
    float* ws, float* out)
{
    extern __shared__ float sm[];
    const int blk = blockIdx.x, t = threadIdx.x;
    phaseA(blk, t, sm, zW, zb, Wq, bq, Wk, Wv, Wo, ce, cc, vW, bo, ws);
    cg::this_grid().sync();
    phaseB(blk, t, sm, bv, ws);
    cg::this_grid().sync();
    phaseC(blk, t, sm, z, rw, geo, vb, ws, out);
}

// ---------------- fallback: separate launches (same phase code) ----------------
__global__ __launch_bounds__(512) void k_pre(
    const float* zW, const float* zb, const float* Wq, const float* bq,
    const float* Wk, const float* Wv, const float* Wo, const float* ce,
    const float* cc, const float* vW, const float* bo, float* ws)
{
    extern __shared__ float sm[];
    phaseA(blockIdx.x, threadIdx.x, sm, zW, zb, Wq, bq, Wk, Wv, Wo, ce, cc, vW, bo, ws);
}

__global__ __launch_bounds__(512) void k_mid(const float* bv, float* ws)
{
    extern __shared__ float sm[];
    phaseB(blockIdx.x, threadIdx.x, sm, bv, ws);
}

__global__ __launch_bounds__(512) void k_main(
    const float* z, const float* rw, const float* geo, const float* vb,
    const float* ws, float* out)
{
    extern __shared__ float sm[];
    phaseC(blockIdx.x, threadIdx.x, sm, z, rw, geo, vb, ws, out);
}

extern "C" void kernel_launch(void* const* d_in, const int* in_sizes, int n_in,
                              void* d_out, int out_size, void* d_ws, size_t ws_size,
                              hipStream_t stream)
{
    (void)in_sizes; (void)n_in; (void)out_size; (void)ws_size;
    const float* z   = (const float*)d_in[0];
    const float* rw  = (const float*)d_in[1];
    const float* cem = (const float*)d_in[2];
    const float* cc  = (const float*)d_in[3];
    const float* zW  = (const float*)d_in[4];
    const float* zb  = (const float*)d_in[5];
    const float* Wq  = (const float*)d_in[6];
    const float* bq  = (const float*)d_in[7];
    const float* Wk  = (const float*)d_in[8];
    // d_in[9] = bk: softmax-shift-invariant, provably unused
    const float* Wv  = (const float*)d_in[10];
    const float* bv  = (const float*)d_in[11];
    const float* Wo  = (const float*)d_in[12];
    const float* bo  = (const float*)d_in[13];
    const float* geo = (const float*)d_in[14];
    const float* vW  = (const float*)d_in[15];
    const float* vb  = (const float*)d_in[16];
    float* ws  = (float*)d_ws;
    float* out = (float*)d_out;

    int coop = 0, dev = 0;
    hipGetDevice(&dev);
    hipDeviceGetAttribute(&coop, hipDeviceAttributeCooperativeLaunch, dev);
    if (coop) {
        void* args[] = {
            (void*)&zW, (void*)&zb, (void*)&Wq, (void*)&bq,
            (void*)&Wk, (void*)&Wv, (void*)&Wo, (void*)&cem,
            (void*)&cc, (void*)&vW, (void*)&bo, (void*)&bv,
            (void*)&z,  (void*)&rw, (void*)&geo, (void*)&vb,
            (void*)&ws, (void*)&out };
        hipError_t e = hipLaunchCooperativeKernel((const void*)k_fused,
                                                  dim3(256), dim3(512),
                                                  args, FUSED_LDSB, stream);
        if (e == hipSuccess) return;
    }
    // fallback: 3 dependent launches
    hipLaunchKernelGGL(k_pre,  dim3(217), dim3(512), FUSED_LDSB, stream,
                       zW, zb, Wq, bq, Wk, Wv, Wo, cem, cc, vW, bo, ws);
    hipLaunchKernelGGL(k_mid,  dim3(7),   dim3(512), FUSED_LDSB, stream, bv, ws);
    hipLaunchKernelGGL(k_main, dim3(256), dim3(512), MAIN_LDSB, stream,
                       z, rw, geo, vb, ws, out);
}

// Round 5
// 66.227 us; speedup vs baseline: 1.4713x; 1.4713x over previous
//
#include <hip/hip_runtime.h>
#include <math.h>

// dims: B=4096, D=64, K=64, DM=512
// Workspace layout (float offsets) — all written by K1, read by K2.
#define WS_BOVW   2
#define WS_N2V    4
#define WS_COLSUM 64          // 64
#define WS_A      128         // 64*64
#define WS_WO0    4224        // 512
#define WS_QZB    4736        // 512
#define WS_NY2    5376        // 64
#define WS_YT     5440        // 4096
#define WS_T1     16384       // T1t[f][k] 512*64
#define WS_V1     49152       // V1t[e][k] 512*64
#define WS_P1     81920       // P1[f][d]  512*64

#define PRE_LDSB  (36928 * 4)   // 147712 B

// K2 LDS layout (floats)
#define YL    0        // 16*512
#define ZL    8192     // 16*64
#define AL    9216     // 64*65
#define QZBL  13376    // 512
#define WO0L  13888    // 512
#define YTL   14400    // 64*64
#define NY2L  18496    // 64
#define PD    18560    // 7*17*64
#define PCV   26176    // 7*64
#define PBV   26624    // 7
#define MISC  26631    // 9
#define K2F   26640
#define K2_LDSB (K2F * 4)       // 106560 B -> 1 block/CU

__device__ __forceinline__ float wave_sum(float x) {
#pragma unroll
    for (int o = 32; o; o >>= 1) x += __shfl_xor(x, o);
    return x;
}

__device__ __forceinline__ float block_sum512(float v, float* red) {
    float s = wave_sum(v);
    const int wid = threadIdx.x >> 6;
    __syncthreads();
    if ((threadIdx.x & 63) == 0) red[wid] = s;
    __syncthreads();
    float t2 = 0.0f;
#pragma unroll
    for (int i = 0; i < 8; ++i) t2 += red[i];
    return t2;
}

// ===========================================================================
// K1: 217 blocks x 512 threads. All level-0 (inputs only). Same as r3 phaseA
// (proven absmax=0) with float4-vectorized CE staging.
// ===========================================================================
__global__ __launch_bounds__(512) void k_pre(
    const float* __restrict__ zW, const float* __restrict__ zb,
    const float* __restrict__ Wq, const float* __restrict__ bq,
    const float* __restrict__ Wk, const float* __restrict__ Wv,
    const float* __restrict__ Wo, const float* __restrict__ ce,
    const float* __restrict__ cc, const float* __restrict__ vW,
    const float* __restrict__ bo, float* __restrict__ ws)
{
    extern __shared__ float sm[];
    const int blk = blockIdx.x, t = threadIdx.x;
    const int lane = t & 63, w = t >> 6;

    if (blk < 128) {
        // ---------------- T1t / V1t ----------------
        const int f0 = blk * 4;
        float* ces = sm;            // 64*513
        float* wkv = sm + 32832;    // 8*512
        {
            const float4* ce4 = (const float4*)ce;
#pragma unroll 4
            for (int i = 0; i < 16; ++i) {
                const int idx4 = i * 512 + t;          // k*128 + c4
                const int k = idx4 >> 7, c4 = idx4 & 127;
                const float4 v = ce4[idx4];
                float* dst = &ces[k * 513 + c4 * 4];
                dst[0] = v.x; dst[1] = v.y; dst[2] = v.z; dst[3] = v.w;
            }
        }
        {
            const float4* Wk4 = (const float4*)Wk;
            const float4* Wv4 = (const float4*)Wv;
            float4* wkv4 = (float4*)wkv;
#pragma unroll
            for (int i = 0; i < 2; ++i) {
                const int idx = i * 512 + t;
                const int a = idx >> 7, c4 = idx & 127;
                wkv4[idx] = (a < 4) ? Wk4[(f0 + a) * 128 + c4]
                                    : Wv4[(f0 + a - 4) * 128 + c4];
            }
        }
        __syncthreads();
        float acc[8];
#pragma unroll
        for (int a = 0; a < 8; ++a) acc[a] = 0.0f;
        const int c0 = w * 64;
#pragma unroll 2
        for (int q4 = 0; q4 < 16; ++q4) {
            const int c = c0 + q4 * 4;
            const float cv0 = ces[lane * 513 + c + 0];
            const float cv1 = ces[lane * 513 + c + 1];
            const float cv2 = ces[lane * 513 + c + 2];
            const float cv3 = ces[lane * 513 + c + 3];
#pragma unroll
            for (int a = 0; a < 8; ++a) {
                const float4 wv4 = *(const float4*)&wkv[a * 512 + c];
                acc[a] = fmaf(wv4.x, cv0, acc[a]);
                acc[a] = fmaf(wv4.y, cv1, acc[a]);
                acc[a] = fmaf(wv4.z, cv2, acc[a]);
                acc[a] = fmaf(wv4.w, cv3, acc[a]);
            }
        }
        __syncthreads();
        float* part = sm;                              // reuse, 64*65
#pragma unroll
        for (int a = 0; a < 8; ++a) part[(a * 8 + w) * 65 + lane] = acc[a];
        __syncthreads();
        {
            float s = 0.0f;
#pragma unroll
            for (int ww = 0; ww < 8; ++ww) s += part[(w * 8 + ww) * 65 + lane];
            if (w < 4) ws[WS_T1 + (f0 + w) * 64 + lane] = s;
            else       ws[WS_V1 + (f0 + w - 4) * 64 + lane] = s;
        }

    } else if (blk < 192) {
        // ---------------- P1 ----------------
        const int f0 = (blk - 128) * 8;
        float* zl = sm;             // 512*64
        float* wq = sm + 32768;     // 8*512
        {
            const float4* zW4 = (const float4*)zW;
            float4* zl4 = (float4*)zl;
#pragma unroll 4
            for (int i = 0; i < 16; ++i) zl4[i * 512 + t] = zW4[i * 512 + t];
            const float4* Wq4 = (const float4*)Wq;
            float4* wq4 = (float4*)wq;
#pragma unroll
            for (int i = 0; i < 2; ++i)
                wq4[i * 512 + t] = Wq4[f0 * 128 + i * 512 + t];
        }
        __syncthreads();
        float acc[8];
#pragma unroll
        for (int a = 0; a < 8; ++a) acc[a] = 0.0f;
        const int e0 = w * 64;
#pragma unroll 2
        for (int q4 = 0; q4 < 16; ++q4) {
            const int e = e0 + q4 * 4;
            const float z0 = zl[(e + 0) * 64 + lane];
            const float z1 = zl[(e + 1) * 64 + lane];
            const float z2 = zl[(e + 2) * 64 + lane];
            const float z3 = zl[(e + 3) * 64 + lane];
#pragma unroll
            for (int fi = 0; fi < 8; ++fi) {
                const float4 q4v = *(const float4*)&wq[fi * 512 + e];
                acc[fi] = fmaf(q4v.x, z0, acc[fi]);
                acc[fi] = fmaf(q4v.y, z1, acc[fi]);
                acc[fi] = fmaf(q4v.z, z2, acc[fi]);
                acc[fi] = fmaf(q4v.w, z3, acc[fi]);
            }
        }
        __syncthreads();
        float* part = sm;
#pragma unroll
        for (int a = 0; a < 8; ++a) part[(a * 8 + w) * 65 + lane] = acc[a];
        __syncthreads();
        {
            float s = 0.0f;
#pragma unroll
            for (int ww = 0; ww < 8; ++ww) s += part[(w * 8 + ww) * 65 + lane];
            ws[WS_P1 + (f0 + w) * 64 + lane] = s;
        }

    } else if (blk < 200) {
        // ---------------- A = zW^T zW (+ colsum on first) ----------------
        const int r0 = (blk - 192) * 8;
        float* zl = sm;
        {
            const float4* zW4 = (const float4*)zW;
            float4* zl4 = (float4*)zl;
#pragma unroll 4
            for (int i = 0; i < 16; ++i) zl4[i * 512 + t] = zW4[i * 512 + t];
        }
        __syncthreads();
        float acc[8];
#pragma unroll
        for (int a = 0; a < 8; ++a) acc[a] = 0.0f;
        float cs = 0.0f;
        const int e0 = w * 64;
#pragma unroll 2
        for (int q4 = 0; q4 < 16; ++q4) {
            const int e = e0 + q4 * 4;
#pragma unroll
            for (int j = 0; j < 4; ++j) {
                const float zv = zl[(e + j) * 64 + lane];
                cs += zv;
                const float4 b0 = *(const float4*)&zl[(e + j) * 64 + r0];
                const float4 b1 = *(const float4*)&zl[(e + j) * 64 + r0 + 4];
                acc[0] = fmaf(b0.x, zv, acc[0]);
                acc[1] = fmaf(b0.y, zv, acc[1]);
                acc[2] = fmaf(b0.z, zv, acc[2]);
                acc[3] = fmaf(b0.w, zv, acc[3]);
                acc[4] = fmaf(b1.x, zv, acc[4]);
                acc[5] = fmaf(b1.y, zv, acc[5]);
                acc[6] = fmaf(b1.z, zv, acc[6]);
                acc[7] = fmaf(b1.w, zv, acc[7]);
            }
        }
        __syncthreads();
        float* part = sm;            // 64*65
        float* part2 = sm + 4160;    // 8*65
#pragma unroll
        for (int a = 0; a < 8; ++a) part[(a * 8 + w) * 65 + lane] = acc[a];
        if (blk == 192) part2[w * 65 + lane] = cs;
        __syncthreads();
        {
            float s = 0.0f;
#pragma unroll
            for (int ww = 0; ww < 8; ++ww) s += part[(w * 8 + ww) * 65 + lane];
            ws[WS_A + (r0 + w) * 64 + lane] = s;
        }
        if (blk == 192 && t < 64) {
            float s = 0.0f;
#pragma unroll
            for (int ww = 0; ww < 8; ++ww) s += part2[ww * 65 + t];
            ws[WS_COLSUM + t] = s;
        }

    } else if (blk < 208) {
        // ---------------- qzb ----------------
        const int f0 = (blk - 200) * 64;
        float zbr[8];
#pragma unroll
        for (int i = 0; i < 8; ++i) zbr[i] = zb[i * 64 + lane];
#pragma unroll
        for (int ff = 0; ff < 8; ++ff) {
            const int f = f0 + w * 8 + ff;
            float s = 0.0f;
#pragma unroll
            for (int i = 0; i < 8; ++i)
                s = fmaf(Wq[f * 512 + i * 64 + lane], zbr[i], s);
            s = wave_sum(s);
            if (lane == 0) ws[WS_QZB + f] = s + bq[f];
        }

    } else if (blk < 216) {
        // ---------------- wo0 = Wo^T vW ----------------
        const int e0 = (blk - 208) * 64;
        float s = 0.0f;
#pragma unroll 4
        for (int gi = 0; gi < 64; ++gi) {
            const int g = w * 64 + gi;
            s = fmaf(Wo[g * 512 + e0 + lane], vW[g], s);
        }
        float* part = sm;
        part[w * 65 + lane] = s;
        __syncthreads();
        if (t < 64) {
            float o = 0.0f;
#pragma unroll
            for (int ww = 0; ww < 8; ++ww) o += part[ww * 65 + t];
            ws[WS_WO0 + e0 + t] = o;
        }

    } else {
        // ---------------- misc: n2v, bo.vW, cc projection ----------------
        float* red = sm;
        const float vwt = vW[t];
        const float n2v = block_sum512(vwt * vwt, red);
        if (t == 0) ws[WS_N2V] = n2v;
        const float bv_ = block_sum512(bo[t] * vwt, red);
        if (t == 0) ws[WS_BOVW] = bv_;
        if (t < 64) {
            float n2 = 0.0f;
            for (int dd = 0; dd < 64; ++dd) {
                const float c = cc[t * 64 + dd];
                n2 = fmaf(c, c, n2);
            }
            const float n = sqrtf(n2);
            const float scale = fminf(1.0f, (1.0f - 1e-5f) / fmaxf(n, 1e-12f));
            float s2 = 0.0f;
            for (int dd = 0; dd < 64; ++dd) {
                const float yv = cc[t * 64 + dd] * scale;
                ws[WS_YT + dd * 64 + t] = yv;
                s2 = fmaf(yv, yv, s2);
            }
            ws[WS_NY2 + t] = s2;
        }
    }
}

// ===========================================================================
// K2: main. 256 blocks x 512 threads, 16 rows/block.
//  stage: z-rows, A, Yt, qzb, wo0, ny2, consts into LDS
//  step2: y[r][f] = P1[f,:].z[r]  (thread owns f-column = t; P1 from L2)
//  step3: wave0: sigma chain (w4=A^4 colsum, closed form) + inv_sv;
//         waves1..7: stream T1/V1 f-slices: dot[r][k], ck0[k], cvw[k], bv.wo
//  final: per-wave 2 rows: geo distance + softmax + out
// ===========================================================================
__global__ __launch_bounds__(512) void k_main(
    const float* __restrict__ z, const float* __restrict__ rw,
    const float* __restrict__ geo, const float* __restrict__ vb,
    const float* __restrict__ bv, const float* __restrict__ ws,
    float* __restrict__ out)
{
    extern __shared__ float sm[];
    const int t = threadIdx.x;
    const int lane = t & 63, w = t >> 6;
    const int b0 = blockIdx.x * 16;

    // ---- stage ----
#pragma unroll
    for (int i = 0; i < 2; ++i) sm[ZL + i * 512 + t] = z[b0 * 64 + i * 512 + t];
#pragma unroll
    for (int i = 0; i < 8; ++i) {
        const int idx = i * 512 + t;
        sm[AL + (idx >> 6) * 65 + (idx & 63)] = ws[WS_A + idx];
        sm[YTL + idx] = ws[WS_YT + idx];
    }
    sm[QZBL + t] = ws[WS_QZB + t];
    sm[WO0L + t] = ws[WS_WO0 + t];
    if (t < 64) sm[NY2L + t] = ws[WS_NY2 + t];
    if (t == 0) {
        sm[MISC + 2] = ws[WS_BOVW];
        sm[MISC + 3] = vb[0];
        sm[MISC + 4] = geo[0];
    }
    __syncthreads();

    // ---- step2: y[r][t] = sum_d P1[t][d] * z[r][d] ----
    {
        float acc[16];
#pragma unroll
        for (int r = 0; r < 16; ++r) acc[r] = 0.0f;
        const float* p1 = ws + WS_P1 + t * 64;
#pragma unroll 4
        for (int dq = 0; dq < 16; ++dq) {
            const float4 pv = *(const float4*)(p1 + dq * 4);
#pragma unroll
            for (int r = 0; r < 16; ++r) {
                const float4 zv = *(const float4*)&sm[ZL + r * 64 + dq * 4];
                acc[r] = fmaf(pv.x, zv.x, acc[r]);
                acc[r] = fmaf(pv.y, zv.y, acc[r]);
                acc[r] = fmaf(pv.z, zv.z, acc[r]);
                acc[r] = fmaf(pv.w, zv.w, acc[r]);
            }
        }
#pragma unroll
        for (int r = 0; r < 16; ++r) sm[YL + r * 512 + t] = acc[r];
    }
    __syncthreads();

    // ---- step3 ----
    if (w == 0) {
        // sigma chain: w4 = A^4 colsum; sigma = n5sq/(n5+eps),
        // n5sq = (w4.A.w4)/(sqrt(w4.w4)+eps)^2   (exact closed form of the
        // normalized power iteration: intermediate l2n only rescales)
        float wv = ws[WS_COLSUM + lane];
#pragma unroll
        for (int it = 0; it < 4; ++it) {
            float mv = 0.0f;
            for (int j = 0; j < 64; ++j)
                mv = fmaf(sm[AL + j * 65 + lane], __shfl(wv, j), mv);
            wv = mv;
        }
        const float s8 = wave_sum(wv * wv);
        float mv = 0.0f;
        for (int j = 0; j < 64; ++j)
            mv = fmaf(sm[AL + j * 65 + lane], __shfl(wv, j), mv);
        const float s9 = wave_sum(mv * wv);
        const float den = sqrtf(s8) + 1e-12f;
        const float n5sq = s9 / (den * den);
        const float n5 = sqrtf(n5sq);
        const float sig = n5sq / (n5 + 1e-12f);
        if (lane == 0) sm[MISC + 0] = 1.0f / sig;
        if (lane == 0) {
            const float n2 = ws[WS_N2V];
            const float rn = sqrtf(n2);
            float u = 1.0f / (1.0f + 1e-12f), s = 0.0f;
            for (int it = 0; it < 5; ++it) {
                const float nv = fabsf(u) * rn;
                const float vs = u / (nv + 1e-12f);
                s = n2 * vs;
                u = s / (fabsf(s) + 1e-12f);
            }
            sm[MISC + 1] = 1.0f / (u * s);
        }
    } else {
        const int m = w - 1;
        const int fs = m * 76;
        const int fe = (m == 6) ? 512 : fs + 76;
        float dotr[16];
#pragma unroll
        for (int r = 0; r < 16; ++r) dotr[r] = 0.0f;
        float ck0p = 0.0f;
        for (int f = fs; f < fe; f += 4) {
            const float t0 = ws[WS_T1 + (f + 0) * 64 + lane];
            const float t1 = ws[WS_T1 + (f + 1) * 64 + lane];
            const float t2 = ws[WS_T1 + (f + 2) * 64 + lane];
            const float t3 = ws[WS_T1 + (f + 3) * 64 + lane];
            const float4 qv = *(const float4*)&sm[QZBL + f];
            ck0p = fmaf(t0, qv.x, ck0p);
            ck0p = fmaf(t1, qv.y, ck0p);
            ck0p = fmaf(t2, qv.z, ck0p);
            ck0p = fmaf(t3, qv.w, ck0p);
#pragma unroll
            for (int r = 0; r < 16; ++r) {
                const float4 yv = *(const float4*)&sm[YL + r * 512 + f];
                dotr[r] = fmaf(t0, yv.x, dotr[r]);
                dotr[r] = fmaf(t1, yv.y, dotr[r]);
                dotr[r] = fmaf(t2, yv.z, dotr[r]);
                dotr[r] = fmaf(t3, yv.w, dotr[r]);
            }
        }
        float cvwp = 0.0f;
        for (int e = fs; e < fe; ++e)
            cvwp = fmaf(ws[WS_V1 + e * 64 + lane], sm[WO0L + e], cvwp);
        float bvw = 0.0f;
        for (int e = fs; e < fe; ++e)
            bvw = fmaf(bv[e], sm[WO0L + e], bvw);
#pragma unroll
        for (int r = 0; r < 16; ++r)
            sm[PD + m * 1088 + r * 64 + lane] = dotr[r];
        sm[PD + m * 1088 + 1024 + lane] = ck0p;
        sm[PCV + m * 64 + lane] = cvwp;
        if (lane == 0) sm[PBV + m] = bvw;
    }
    __syncthreads();

    // ---- final: wave w -> rows 2w, 2w+1 ----
    const float inv_s = sm[MISC + 0];
    const float inv_sv = sm[MISC + 1];
    float bvwo = 0.0f;
#pragma unroll
    for (int m = 0; m < 7; ++m) bvwo += sm[PBV + m];
    const float cst = inv_sv * (bvwo + sm[MISC + 2]) + sm[MISC + 3];
    const float gs = sm[MISC + 4];
    float ck0 = 0.0f, cvw = 0.0f;
#pragma unroll
    for (int m = 0; m < 7; ++m) {
        ck0 += sm[PD + m * 1088 + 1024 + lane];
        cvw += sm[PCV + m * 64 + lane];
    }
    cvw *= inv_sv;
    const float ny2 = sm[NY2L + lane];
    const float rs512 = 0.04419417382415922f;   // 1/sqrt(512)
#pragma unroll
    for (int rr = 0; rr < 2; ++rr) {
        const int r = w * 2 + rr;
        const int b = b0 + r;
        const float rwk = rw[b * 64 + lane];
        float dacc = 0.0f;
#pragma unroll
        for (int m = 0; m < 7; ++m) dacc += sm[PD + m * 1088 + r * 64 + lane];
        const float dot = inv_s * dacc;
        float diff2 = 0.0f, nz2 = 0.0f;
#pragma unroll 8
        for (int dd = 0; dd < 64; ++dd) {
            const float zd = sm[ZL + r * 64 + dd];
            nz2 = fmaf(zd, zd, nz2);
            const float df = zd - sm[YTL + dd * 64 + lane];
            diff2 = fmaf(df, df, diff2);
        }
        const float den = (1.0f - nz2) * (1.0f - ny2);
        float arg = 1.0f + 2.0f * diff2 / fmaxf(den, 1e-12f);
        arg = fmaxf(arg, 1.0f + 1e-7f);
        const float dg = acoshf(arg);
        const float score = rwk * (dot + ck0) * rs512 - gs * dg * dg;
        float mx = score;
#pragma unroll
        for (int o = 32; o; o >>= 1) mx = fmaxf(mx, __shfl_xor(mx, o));
        const float e = expf(score - mx);
        float s1 = e, s2 = e * rwk * cvw;
#pragma unroll
        for (int o = 32; o; o >>= 1) { s1 += __shfl_xor(s1, o); s2 += __shfl_xor(s2, o); }
        if (lane == 0) out[b] = s2 / s1 + cst;
    }
}

extern "C" void kernel_launch(void* const* d_in, const int* in_sizes, int n_in,
                              void* d_out, int out_size, void* d_ws, size_t ws_size,
                              hipStream_t stream)
{
    (void)in_sizes; (void)n_in; (void)out_size; (void)ws_size;
    const float* z   = (const float*)d_in[0];
    const float* rw  = (const float*)d_in[1];
    const float* cem = (const float*)d_in[2];
    const float* cc  = (const float*)d_in[3];
    const float* zW  = (const float*)d_in[4];
    const float* zb  = (const float*)d_in[5];
    const float* Wq  = (const float*)d_in[6];
    const float* bq  = (const float*)d_in[7];
    const float* Wk  = (const float*)d_in[8];
    // d_in[9] = bk: softmax-shift-invariant, provably unused
    const float* Wv  = (const float*)d_in[10];
    const float* bv  = (const float*)d_in[11];
    const float* Wo  = (const float*)d_in[12];
    const float* bo  = (const float*)d_in[13];
    const float* geo = (const float*)d_in[14];
    const float* vW  = (const float*)d_in[15];
    const float* vb  = (const float*)d_in[16];
    float* ws  = (float*)d_ws;
    float* out = (float*)d_out;

    hipLaunchKernelGGL(k_pre,  dim3(217), dim3(512), PRE_LDSB, stream,
                       zW, zb, Wq, bq, Wk, Wv, Wo, cem, cc, vW, bo, ws);
    hipLaunchKernelGGL(k_main, dim3(256), dim3(512), K2_LDSB, stream,
                       z, rw, geo, vb, bv, ws, out);
}